// Round 2
// baseline (877.844 us; speedup 1.0000x reference)
//
#include <hip/hip_runtime.h>
#include <hip/hip_bf16.h>

#define N_NODES 8192

typedef __attribute__((ext_vector_type(8))) short short8;
typedef __attribute__((ext_vector_type(4))) float floatx4;

__device__ inline unsigned short f2bf(float f) {
  unsigned int u = __float_as_uint(f);
  u = (u + 0x7FFFu + ((u >> 16) & 1u)) >> 16;  // RNE, no NaNs in this data
  return (unsigned short)u;
}

__device__ inline short8 cvt8(const float4 lo, const float4 hi) {
  short8 r;
  r[0] = (short)f2bf(lo.x); r[1] = (short)f2bf(lo.y);
  r[2] = (short)f2bf(lo.z); r[3] = (short)f2bf(lo.w);
  r[4] = (short)f2bf(hi.x); r[5] = (short)f2bf(hi.y);
  r[6] = (short)f2bf(hi.z); r[7] = (short)f2bf(hi.w);
  return r;
}

__device__ inline float waveSum(float s) {
#pragma unroll
  for (int off = 32; off >= 1; off >>= 1) s += __shfl_xor(s, off, 64);
  return s;
}

__device__ inline void acc4(float4& a, const float4 b) {
  a.x += b.x; a.y += b.y; a.z += b.z; a.w += b.w;
}
__device__ inline float hsum4(const float4 v) { return v.x + v.y + v.z + v.w; }

// ---------------------------------------------------------------------------
// k_rowsum: one matrix; dinv[row] = rsqrt(1 + rowsum). wave/row, grid 2048x256
// ---------------------------------------------------------------------------
__global__ __launch_bounds__(256) void k_rowsum(const float* __restrict__ A,
                                                float* __restrict__ dv) {
  int w = threadIdx.x >> 6, l = threadIdx.x & 63;
  long row = (long)blockIdx.x * 4 + w;
  const float* rp = A + row * N_NODES + 4 * l;
  float s = 0.f;
#pragma unroll 2
  for (int i = 0; i < 32; i += 4) {
    float4 v0 = *(const float4*)(rp + 256 * (i + 0));
    float4 v1 = *(const float4*)(rp + 256 * (i + 1));
    float4 v2 = *(const float4*)(rp + 256 * (i + 2));
    float4 v3 = *(const float4*)(rp + 256 * (i + 3));
    s += hsum4(v0) + hsum4(v1) + hsum4(v2) + hsum4(v3);
  }
  s = waveSum(s);
  if (l == 0) dv[row] = rsqrtf(1.0f + s);
}

// ---------------------------------------------------------------------------
// k_uc_partials: one pass over adj_uc -> row partials + col partials (no atomics)
// grid (64, 8) x 256
// ---------------------------------------------------------------------------
__global__ __launch_bounds__(256) void k_uc_partials(const float* __restrict__ adj,
                                                     float* __restrict__ rs_part,
                                                     float* __restrict__ cs_part) {
  __shared__ float cacc[4][1024];
  int t = threadIdx.x, w = t >> 6, l = t & 63;
  int rc = blockIdx.x, cc = blockIdx.y;
  int c0 = cc * 1024;
  int rbase = rc * 128 + w * 32;
  float4 ca0 = {0, 0, 0, 0}, ca1 = {0, 0, 0, 0}, ca2 = {0, 0, 0, 0}, ca3 = {0, 0, 0, 0};
  for (int kr = 0; kr < 32; kr += 2) {
    const float* p0 = adj + (long)(rbase + kr) * N_NODES + c0 + 4 * l;
    const float* p1 = p0 + N_NODES;
    float4 u0 = *(const float4*)(p0 + 0);
    float4 u1 = *(const float4*)(p0 + 256);
    float4 u2 = *(const float4*)(p0 + 512);
    float4 u3 = *(const float4*)(p0 + 768);
    float4 v0 = *(const float4*)(p1 + 0);
    float4 v1 = *(const float4*)(p1 + 256);
    float4 v2 = *(const float4*)(p1 + 512);
    float4 v3 = *(const float4*)(p1 + 768);
    acc4(ca0, u0); acc4(ca1, u1); acc4(ca2, u2); acc4(ca3, u3);
    acc4(ca0, v0); acc4(ca1, v1); acc4(ca2, v2); acc4(ca3, v3);
    float s0 = hsum4(u0) + hsum4(u1) + hsum4(u2) + hsum4(u3);
    float s1 = hsum4(v0) + hsum4(v1) + hsum4(v2) + hsum4(v3);
    s0 = waveSum(s0);
    s1 = waveSum(s1);
    if (l == 0) {
      rs_part[(long)cc * N_NODES + rbase + kr] = s0;
      rs_part[(long)cc * N_NODES + rbase + kr + 1] = s1;
    }
  }
  *(float4*)&cacc[w][0 + 4 * l] = ca0;
  *(float4*)&cacc[w][256 + 4 * l] = ca1;
  *(float4*)&cacc[w][512 + 4 * l] = ca2;
  *(float4*)&cacc[w][768 + 4 * l] = ca3;
  __syncthreads();
#pragma unroll
  for (int i = 0; i < 4; ++i) {
    int c = t + 256 * i;
    cs_part[(long)rc * N_NODES + c0 + c] = cacc[0][c] + cacc[1][c] + cacc[2][c] + cacc[3][c];
  }
}

// ---------------------------------------------------------------------------
// k_finalize: du = rsqrt(rowsum(adj_uc)), dc = rsqrt(colsum(adj_uc)). grid 32
// ---------------------------------------------------------------------------
__global__ __launch_bounds__(256) void k_finalize(const float* __restrict__ rs_part,
                                                  const float* __restrict__ cs_part,
                                                  float* __restrict__ du,
                                                  float* __restrict__ dc) {
  int i = blockIdx.x * 256 + threadIdx.x;
  float s = 0.f;
#pragma unroll
  for (int cc = 0; cc < 8; ++cc) s += rs_part[(long)cc * N_NODES + i];
  du[i] = rsqrtf(s);
  float c = 0.f;
#pragma unroll
  for (int rc = 0; rc < 64; ++rc) c += cs_part[(long)rc * N_NODES + i];
  dc[i] = rsqrtf(c);
}

// ---------------------------------------------------------------------------
// k_projw: P = proj_u @ weight_c (32x32). one block x 1024
// ---------------------------------------------------------------------------
__global__ void k_projw(const float* __restrict__ proj_u,
                        const float* __restrict__ weight_c, float* __restrict__ P) {
  int t = threadIdx.x;
  int i = t >> 5, j = t & 31;
  float s = 0.f;
#pragma unroll
  for (int k = 0; k < 32; ++k) s += proj_u[i * 32 + k] * weight_c[k * 32 + j];
  P[t] = s;
}

// ---------------------------------------------------------------------------
// k_support: Bt[n][j] = bf16( dv[j] * (X @ W)[j][n] ), transposed bf16 output.
// grid 1024 x 256 (8 rows x 32 cols per block)
// ---------------------------------------------------------------------------
__global__ __launch_bounds__(256) void k_support(const float* __restrict__ X,
                                                 const float* __restrict__ W,
                                                 const float* __restrict__ dv,
                                                 short* __restrict__ bt) {
  __shared__ float Wl[32][32];
  __shared__ float Xl[8][32];
  int t = threadIdx.x;
#pragma unroll
  for (int i = 0; i < 4; ++i) {
    int idx = t + 256 * i;
    Wl[idx >> 5][idx & 31] = W[idx];
  }
  int r = t >> 5, n = t & 31;
  int j0 = blockIdx.x * 8;
  Xl[r][n] = X[(long)(j0 + r) * 32 + n];
  __syncthreads();
  float s = 0.f;
#pragma unroll
  for (int k = 0; k < 32; ++k) s += Xl[r][k] * Wl[k][n];
  s *= dv[j0 + r];
  bt[(long)n * N_NODES + j0 + r] = (short)f2bf(s);
}

// ---------------------------------------------------------------------------
// k_gemm_wave: part[kh][i][n] = sum_{k in half kh} adj[i,k]*bt[n][k]
// Barrier-free, LDS-free. Wave owns 16 rows x 32 cols; A fp32->bf16 in regs;
// B from L2-hot bt (512 KB). Register pipeline depth 2 (64 k / outer iter).
// K split in halves -> 1024 waves/matrix = 4 waves/CU for latency hiding.
// grid 1024 x 64
// ---------------------------------------------------------------------------
__global__ __launch_bounds__(64) void k_gemm_wave(const float* __restrict__ adj,
                                                  const short* __restrict__ bt,
                                                  float* __restrict__ part) {
  int l = threadIdx.x;
  int bx = blockIdx.x;
  int kh = bx & 1;                 // K half
  long r0 = (long)(bx >> 1) * 16;  // row tile
  int m = l & 15, q = l >> 4;

  const float* ap = adj + (r0 + m) * N_NODES + kh * 4096 + q * 8;
  const short* b0p = bt + (long)m * N_NODES + kh * 4096 + q * 8;
  const short* b1p = b0p + 16L * N_NODES;

  floatx4 acc0 = {0.f, 0.f, 0.f, 0.f}, acc1 = {0.f, 0.f, 0.f, 0.f};

  // prime pipeline: slot0 @ k-offset 0, slot1 @ k-offset 32
  float4 c0lo = *(const float4*)(ap + 0);
  float4 c0hi = *(const float4*)(ap + 4);
  short8 d00 = *(const short8*)(b0p + 0);
  short8 d10 = *(const short8*)(b1p + 0);
  float4 c1lo = *(const float4*)(ap + 32);
  float4 c1hi = *(const float4*)(ap + 36);
  short8 d01 = *(const short8*)(b0p + 32);
  short8 d11 = *(const short8*)(b1p + 32);

  for (int it = 0; it < 63; ++it) {
    ap += 64; b0p += 64; b1p += 64;
    short8 af0 = cvt8(c0lo, c0hi);
    acc0 = __builtin_amdgcn_mfma_f32_16x16x32_bf16(af0, d00, acc0, 0, 0, 0);
    acc1 = __builtin_amdgcn_mfma_f32_16x16x32_bf16(af0, d10, acc1, 0, 0, 0);
    c0lo = *(const float4*)(ap + 0);
    c0hi = *(const float4*)(ap + 4);
    d00 = *(const short8*)(b0p + 0);
    d10 = *(const short8*)(b1p + 0);
    short8 af1 = cvt8(c1lo, c1hi);
    acc0 = __builtin_amdgcn_mfma_f32_16x16x32_bf16(af1, d01, acc0, 0, 0, 0);
    acc1 = __builtin_amdgcn_mfma_f32_16x16x32_bf16(af1, d11, acc1, 0, 0, 0);
    c1lo = *(const float4*)(ap + 32);
    c1hi = *(const float4*)(ap + 36);
    d01 = *(const short8*)(b0p + 32);
    d11 = *(const short8*)(b1p + 32);
  }
  {
    short8 af0 = cvt8(c0lo, c0hi);
    acc0 = __builtin_amdgcn_mfma_f32_16x16x32_bf16(af0, d00, acc0, 0, 0, 0);
    acc1 = __builtin_amdgcn_mfma_f32_16x16x32_bf16(af0, d10, acc1, 0, 0, 0);
    short8 af1 = cvt8(c1lo, c1hi);
    acc0 = __builtin_amdgcn_mfma_f32_16x16x32_bf16(af1, d01, acc0, 0, 0, 0);
    acc1 = __builtin_amdgcn_mfma_f32_16x16x32_bf16(af1, d11, acc1, 0, 0, 0);
  }

  // C/D layout (verified m89): col = lane&15, row = (lane>>4)*4 + reg
  float* pp = part + (long)kh * 262144 + (r0 + q * 4) * 32;
#pragma unroll
  for (int r = 0; r < 4; ++r) {
    pp[r * 32 + m] = acc0[r];
    pp[r * 32 + 16 + m] = acc1[r];
  }
}

// ---------------------------------------------------------------------------
// k_epilogue: combine K-halves, apply outer scales, attention, softmax, outputs.
// out sections: [0]=node_embed_u, [1]=node_embed_c, [2]=Y_c, [3]=Y_u
// grid 1024 x 256 (8 rows x 32 lanes)
// ---------------------------------------------------------------------------
__global__ __launch_bounds__(256) void k_epilogue(
    const float* __restrict__ pu, const float* __restrict__ pc,
    const float* __restrict__ pq, const float* __restrict__ dinv_uu,
    const float* __restrict__ dinv_cc, const float* __restrict__ du,
    const float* __restrict__ X_C, const float* __restrict__ W_lin,
    const float* __restrict__ a_vec, float* __restrict__ out) {
  __shared__ float Wl[64][32];
  __shared__ float al[32];
  int t = threadIdx.x;
#pragma unroll
  for (int i = 0; i < 8; ++i) {
    int idx = t + 256 * i;
    Wl[idx >> 5][idx & 31] = W_lin[idx];
  }
  if (t < 32) al[t] = a_vec[t];
  int g = t >> 5, n = t & 31;
  long row = (long)blockIdx.x * 8 + g;
  long o = row * 32 + n;
  __syncthreads();

  out[o] = dinv_uu[row] * (pu[o] + pu[262144 + o]);  // node_embed_u

  float h1 = dinv_cc[row] * (pc[o] + pc[262144 + o]);
  float h2 = du[row] * (pq[o] + pq[262144 + o]);
  float xv = X_C[o];
  float s1 = 0.f, s2 = 0.f, sx = 0.f;
#pragma unroll
  for (int k = 0; k < 32; ++k) {
    float h1k = __shfl(h1, k, 32);
    float h2k = __shfl(h2, k, 32);
    float xk = __shfl(xv, k, 32);
    float w0 = Wl[k][n], w1 = Wl[32 + k][n];
    s1 += h1k * w0;
    s2 += h2k * w0;
    sx += xk * w1;
  }
  float t1 = fmaxf(s1 + sx, 0.f) * al[n];
  float t2 = fmaxf(s2 + sx, 0.f) * al[n];
#pragma unroll
  for (int off = 16; off >= 1; off >>= 1) {
    t1 += __shfl_xor(t1, off, 32);
    t2 += __shfl_xor(t2, off, 32);
  }
  float mx = fmaxf(t1, t2);
  float e1 = expf(t1 - mx), e2 = expf(t2 - mx);
  float inv = 1.0f / (e1 + e2);
  float yc = e1 * inv * h1, yu = e2 * inv * h2;
  out[262144 + o] = yc + yu;  // node_embed_c
  out[524288 + o] = yc;       // Y_c
  out[786432 + o] = yu;       // Y_u
}

extern "C" void kernel_launch(void* const* d_in, const int* in_sizes, int n_in,
                              void* d_out, int out_size, void* d_ws, size_t ws_size,
                              hipStream_t stream) {
  (void)in_sizes; (void)n_in; (void)out_size; (void)ws_size;
  const float* X_U = (const float*)d_in[0];
  const float* X_C = (const float*)d_in[1];
  const float* adj_uu = (const float*)d_in[2];
  const float* adj_uc = (const float*)d_in[3];
  const float* adj_cc = (const float*)d_in[4];
  const float* weight_s = (const float*)d_in[5];
  const float* proj_u = (const float*)d_in[6];
  // d_in[7] = proj_c, unused in forward math
  const float* weight_c = (const float*)d_in[8];
  const float* W_lin = (const float*)d_in[9];
  const float* a_vec = (const float*)d_in[10];
  float* out = (float*)d_out;

  char* ws = (char*)d_ws;
  auto alloc = [&](size_t bytes) {
    char* p = ws;
    ws += (bytes + 255) & ~(size_t)255;
    return p;
  };
  float* dinv_uu = (float*)alloc(8192 * 4);
  float* dinv_cc = (float*)alloc(8192 * 4);
  float* du = (float*)alloc(8192 * 4);
  float* dc = (float*)alloc(8192 * 4);
  float* rs_part = (float*)alloc((size_t)8 * 8192 * 4);
  float* cs_part = (float*)alloc((size_t)64 * 8192 * 4);
  float* P = (float*)alloc(1024 * 4);
  float* pu = (float*)alloc((size_t)2 * 262144 * 4);
  float* pc = (float*)alloc((size_t)2 * 262144 * 4);
  float* pq = (float*)alloc((size_t)2 * 262144 * 4);
  short* bt_uu = (short*)alloc((size_t)262144 * 2);
  short* bt_cc = (short*)alloc((size_t)262144 * 2);
  short* bt_uc = (short*)alloc((size_t)262144 * 2);

  // P is independent; launch first
  hipLaunchKernelGGL(k_projw, dim3(1), dim3(1024), 0, stream, proj_u, weight_c, P);

  // --- adj_uu: rowsum pass warms L3 (256 MB = L3 size), gemm re-reads warm ---
  hipLaunchKernelGGL(k_rowsum, dim3(2048), dim3(256), 0, stream, adj_uu, dinv_uu);
  hipLaunchKernelGGL(k_support, dim3(1024), dim3(256), 0, stream,
                     X_U, weight_s, dinv_uu, bt_uu);
  hipLaunchKernelGGL(k_gemm_wave, dim3(1024), dim3(64), 0, stream, adj_uu, bt_uu, pu);

  // --- adj_cc ---
  hipLaunchKernelGGL(k_rowsum, dim3(2048), dim3(256), 0, stream, adj_cc, dinv_cc);
  hipLaunchKernelGGL(k_support, dim3(1024), dim3(256), 0, stream,
                     X_C, weight_s, dinv_cc, bt_cc);
  hipLaunchKernelGGL(k_gemm_wave, dim3(1024), dim3(64), 0, stream, adj_cc, bt_cc, pc);

  // --- adj_uc ---
  hipLaunchKernelGGL(k_uc_partials, dim3(64, 8), dim3(256), 0, stream,
                     adj_uc, rs_part, cs_part);
  hipLaunchKernelGGL(k_finalize, dim3(32), dim3(256), 0, stream,
                     rs_part, cs_part, du, dc);
  hipLaunchKernelGGL(k_support, dim3(1024), dim3(256), 0, stream, X_U, P, dc, bt_uc);
  hipLaunchKernelGGL(k_gemm_wave, dim3(1024), dim3(64), 0, stream, adj_uc, bt_uc, pq);

  hipLaunchKernelGGL(k_epilogue, dim3(1024), dim3(256), 0, stream,
                     pu, pc, pq, dinv_uu, dinv_cc, du, X_C, W_lin, a_vec, out);
}

// Round 3
// 877.343 us; speedup vs baseline: 1.0006x; 1.0006x over previous
//
#include <hip/hip_runtime.h>
#include <hip/hip_bf16.h>

#define N_NODES 8192

typedef __attribute__((ext_vector_type(8))) short short8;
typedef __attribute__((ext_vector_type(4))) float floatx4;

__device__ inline unsigned short f2bf(float f) {
  unsigned int u = __float_as_uint(f);
  u = (u + 0x7FFFu + ((u >> 16) & 1u)) >> 16;  // RNE, no NaNs in this data
  return (unsigned short)u;
}

__device__ inline short8 cvt8(const float4 lo, const float4 hi) {
  short8 r;
  r[0] = (short)f2bf(lo.x); r[1] = (short)f2bf(lo.y);
  r[2] = (short)f2bf(lo.z); r[3] = (short)f2bf(lo.w);
  r[4] = (short)f2bf(hi.x); r[5] = (short)f2bf(hi.y);
  r[6] = (short)f2bf(hi.z); r[7] = (short)f2bf(hi.w);
  return r;
}

__device__ inline float waveSum(float s) {
#pragma unroll
  for (int off = 32; off >= 1; off >>= 1) s += __shfl_xor(s, off, 64);
  return s;
}

__device__ inline void acc4(float4& a, const float4 b) {
  a.x += b.x; a.y += b.y; a.z += b.z; a.w += b.w;
}
__device__ inline float hsum4(const float4 v) { return v.x + v.y + v.z + v.w; }

// ---------------------------------------------------------------------------
// k_degrees: one pass over all three adjacencies (768 MB).
//  blocks [0,2048): uu rowsum -> dinv_uu      (4 rows/block, wave per row)
//  blocks [2048,4096): cc rowsum -> dinv_cc
//  blocks [4096,4608): uc row+col partials (rc = idx&63, cc = idx>>6)
// grid 4608 x 256
// ---------------------------------------------------------------------------
__global__ __launch_bounds__(256) void k_degrees(
    const float* __restrict__ adj_uu, const float* __restrict__ adj_cc,
    const float* __restrict__ adj_uc, float* __restrict__ dinv_uu,
    float* __restrict__ dinv_cc, float* __restrict__ rs_part,
    float* __restrict__ cs_part) {
  __shared__ float cacc[4][1024];
  int b = blockIdx.x;
  int t = threadIdx.x, w = t >> 6, l = t & 63;
  if (b < 4096) {
    const float* A = (b < 2048) ? adj_uu : adj_cc;
    float* dv = (b < 2048) ? dinv_uu : dinv_cc;
    long row = (long)(b & 2047) * 4 + w;
    const float* rp = A + row * N_NODES + 4 * l;
    float s = 0.f;
#pragma unroll 2
    for (int i = 0; i < 32; i += 4) {
      float4 v0 = *(const float4*)(rp + 256 * (i + 0));
      float4 v1 = *(const float4*)(rp + 256 * (i + 1));
      float4 v2 = *(const float4*)(rp + 256 * (i + 2));
      float4 v3 = *(const float4*)(rp + 256 * (i + 3));
      s += hsum4(v0) + hsum4(v1) + hsum4(v2) + hsum4(v3);
    }
    s = waveSum(s);
    if (l == 0) dv[row] = rsqrtf(1.0f + s);
    return;
  }
  int idx = b - 4096;
  int rc = idx & 63, cc = idx >> 6;
  int c0 = cc * 1024;
  int rbase = rc * 128 + w * 32;
  float4 ca0 = {0, 0, 0, 0}, ca1 = {0, 0, 0, 0}, ca2 = {0, 0, 0, 0}, ca3 = {0, 0, 0, 0};
  for (int kr = 0; kr < 32; kr += 2) {
    const float* p0 = adj_uc + (long)(rbase + kr) * N_NODES + c0 + 4 * l;
    const float* p1 = p0 + N_NODES;
    float4 u0 = *(const float4*)(p0 + 0);
    float4 u1 = *(const float4*)(p0 + 256);
    float4 u2 = *(const float4*)(p0 + 512);
    float4 u3 = *(const float4*)(p0 + 768);
    float4 v0 = *(const float4*)(p1 + 0);
    float4 v1 = *(const float4*)(p1 + 256);
    float4 v2 = *(const float4*)(p1 + 512);
    float4 v3 = *(const float4*)(p1 + 768);
    acc4(ca0, u0); acc4(ca1, u1); acc4(ca2, u2); acc4(ca3, u3);
    acc4(ca0, v0); acc4(ca1, v1); acc4(ca2, v2); acc4(ca3, v3);
    float s0 = hsum4(u0) + hsum4(u1) + hsum4(u2) + hsum4(u3);
    float s1 = hsum4(v0) + hsum4(v1) + hsum4(v2) + hsum4(v3);
    s0 = waveSum(s0);
    s1 = waveSum(s1);
    if (l == 0) {
      rs_part[(long)cc * N_NODES + rbase + kr] = s0;
      rs_part[(long)cc * N_NODES + rbase + kr + 1] = s1;
    }
  }
  *(float4*)&cacc[w][0 + 4 * l] = ca0;
  *(float4*)&cacc[w][256 + 4 * l] = ca1;
  *(float4*)&cacc[w][512 + 4 * l] = ca2;
  *(float4*)&cacc[w][768 + 4 * l] = ca3;
  __syncthreads();
#pragma unroll
  for (int i = 0; i < 4; ++i) {
    int c = t + 256 * i;
    cs_part[(long)rc * N_NODES + c0 + c] = cacc[0][c] + cacc[1][c] + cacc[2][c] + cacc[3][c];
  }
}

// ---------------------------------------------------------------------------
// k_support: Bt[n][j] = bf16( dv[j] * S[j][n] ), transposed bf16.
//  m=0: S = X_U@weight_s, dv=dinv_uu   m=1: S = X_C@weight_s, dv=dinv_cc
//  m=2: S = (X_U@proj_u)@weight_c, dv = dc computed in-block from cs_part
// grid (1024,3) x 256 (8 rows x 32 cols per block)
// ---------------------------------------------------------------------------
__global__ __launch_bounds__(256) void k_support(
    const float* __restrict__ X_U, const float* __restrict__ X_C,
    const float* __restrict__ weight_s, const float* __restrict__ proj_u,
    const float* __restrict__ weight_c, const float* __restrict__ dinv_uu,
    const float* __restrict__ dinv_cc, const float* __restrict__ cs_part,
    short* __restrict__ bt_uu, short* __restrict__ bt_cc,
    short* __restrict__ bt_uc) {
  int m = blockIdx.y;
  __shared__ float W1[32][32];
  __shared__ float W2[32][32];
  __shared__ float Xl[8][32];
  __shared__ float Tl[8][32];
  int t = threadIdx.x;
  const float* X = (m == 1) ? X_C : X_U;
  const float* Wa = (m == 2) ? proj_u : weight_s;
#pragma unroll
  for (int i = 0; i < 4; ++i) {
    int idx = t + 256 * i;
    W1[idx >> 5][idx & 31] = Wa[idx];
  }
  if (m == 2) {
#pragma unroll
    for (int i = 0; i < 4; ++i) {
      int idx = t + 256 * i;
      W2[idx >> 5][idx & 31] = weight_c[idx];
    }
  }
  int r = t >> 5, n = t & 31;
  int j0 = blockIdx.x * 8;
  int j = j0 + r;
  Xl[r][n] = X[(long)j * 32 + n];
  __syncthreads();
  float s = 0.f;
#pragma unroll
  for (int k = 0; k < 32; ++k) s += Xl[r][k] * W1[k][n];
  float dv;
  if (m == 0) {
    dv = dinv_uu[j];
  } else if (m == 1) {
    dv = dinv_cc[j];
  } else {
    Tl[r][n] = s;
    __syncthreads();  // m uniform per block: no divergent barrier
    s = 0.f;
#pragma unroll
    for (int k = 0; k < 32; ++k) s += Tl[r][k] * W2[k][n];
    float p = cs_part[(long)n * N_NODES + j] + cs_part[(long)(n + 32) * N_NODES + j];
#pragma unroll
    for (int off = 16; off >= 1; off >>= 1) p += __shfl_xor(p, off, 32);
    dv = rsqrtf(p);
  }
  short* bt = (m == 0) ? bt_uu : (m == 1) ? bt_cc : bt_uc;
  bt[(long)n * N_NODES + j] = (short)f2bf(s * dv);
}

// ---------------------------------------------------------------------------
// k_gemm: part[kh][i][n] = sum_{k in half kh} adj[i,k]*bt[n][k] for all 3 mats.
// Barrier-free, LDS-free. Wave owns 16 rows x 32 cols x K/2; A fp32->bf16 in
// regs; B from L2-hot bt. Register pipeline depth 2.
// grid 768 x 256: block b -> matrix b>>8; 4 waves/block, 3 blocks/CU exactly,
// 12 waves/CU for latency hiding.
// ---------------------------------------------------------------------------
__global__ __launch_bounds__(256) void k_gemm(
    const float* __restrict__ adj_uu, const float* __restrict__ adj_cc,
    const float* __restrict__ adj_uc, const short* __restrict__ bt_uu,
    const short* __restrict__ bt_cc, const short* __restrict__ bt_uc,
    float* __restrict__ pu, float* __restrict__ pc, float* __restrict__ pq) {
  int b = blockIdx.x;
  int mm = b >> 8;
  const float* adj = (mm == 0) ? adj_uu : (mm == 1) ? adj_cc : adj_uc;
  const short* bt = (mm == 0) ? bt_uu : (mm == 1) ? bt_cc : bt_uc;
  float* part = (mm == 0) ? pu : (mm == 1) ? pc : pq;

  int w = threadIdx.x >> 6, l = threadIdx.x & 63;
  int g = (b & 255) * 4 + w;       // 0..1023: wave task id
  int kh = g & 1;                  // K half
  long r0 = (long)(g >> 1) * 16;   // row tile
  int m = l & 15, q = l >> 4;

  const float* ap = adj + (r0 + m) * N_NODES + kh * 4096 + q * 8;
  const short* b0p = bt + (long)m * N_NODES + kh * 4096 + q * 8;
  const short* b1p = b0p + 16L * N_NODES;

  floatx4 acc0 = {0.f, 0.f, 0.f, 0.f}, acc1 = {0.f, 0.f, 0.f, 0.f};

  float4 c0lo = *(const float4*)(ap + 0);
  float4 c0hi = *(const float4*)(ap + 4);
  short8 d00 = *(const short8*)(b0p + 0);
  short8 d10 = *(const short8*)(b1p + 0);
  float4 c1lo = *(const float4*)(ap + 32);
  float4 c1hi = *(const float4*)(ap + 36);
  short8 d01 = *(const short8*)(b0p + 32);
  short8 d11 = *(const short8*)(b1p + 32);

  for (int it = 0; it < 63; ++it) {
    ap += 64; b0p += 64; b1p += 64;
    short8 af0 = cvt8(c0lo, c0hi);
    acc0 = __builtin_amdgcn_mfma_f32_16x16x32_bf16(af0, d00, acc0, 0, 0, 0);
    acc1 = __builtin_amdgcn_mfma_f32_16x16x32_bf16(af0, d10, acc1, 0, 0, 0);
    c0lo = *(const float4*)(ap + 0);
    c0hi = *(const float4*)(ap + 4);
    d00 = *(const short8*)(b0p + 0);
    d10 = *(const short8*)(b1p + 0);
    short8 af1 = cvt8(c1lo, c1hi);
    acc0 = __builtin_amdgcn_mfma_f32_16x16x32_bf16(af1, d01, acc0, 0, 0, 0);
    acc1 = __builtin_amdgcn_mfma_f32_16x16x32_bf16(af1, d11, acc1, 0, 0, 0);
    c1lo = *(const float4*)(ap + 32);
    c1hi = *(const float4*)(ap + 36);
    d01 = *(const short8*)(b0p + 32);
    d11 = *(const short8*)(b1p + 32);
  }
  {
    short8 af0 = cvt8(c0lo, c0hi);
    acc0 = __builtin_amdgcn_mfma_f32_16x16x32_bf16(af0, d00, acc0, 0, 0, 0);
    acc1 = __builtin_amdgcn_mfma_f32_16x16x32_bf16(af0, d10, acc1, 0, 0, 0);
    short8 af1 = cvt8(c1lo, c1hi);
    acc0 = __builtin_amdgcn_mfma_f32_16x16x32_bf16(af1, d01, acc0, 0, 0, 0);
    acc1 = __builtin_amdgcn_mfma_f32_16x16x32_bf16(af1, d11, acc1, 0, 0, 0);
  }

  // C/D layout (verified m89): col = lane&15, row = (lane>>4)*4 + reg
  float* pp = part + (long)kh * 262144 + (r0 + q * 4) * 32;
#pragma unroll
  for (int r = 0; r < 4; ++r) {
    pp[r * 32 + m] = acc0[r];
    pp[r * 32 + 16 + m] = acc1[r];
  }
}

// ---------------------------------------------------------------------------
// k_epilogue: combine K-halves, outer scales (du from rs_part inline),
// attention, softmax, outputs. grid 1024 x 256 (8 rows x 32 lanes)
// out: [0]=node_embed_u, [1]=node_embed_c, [2]=Y_c, [3]=Y_u
// ---------------------------------------------------------------------------
__global__ __launch_bounds__(256) void k_epilogue(
    const float* __restrict__ pu, const float* __restrict__ pc,
    const float* __restrict__ pq, const float* __restrict__ dinv_uu,
    const float* __restrict__ dinv_cc, const float* __restrict__ rs_part,
    const float* __restrict__ X_C, const float* __restrict__ W_lin,
    const float* __restrict__ a_vec, float* __restrict__ out) {
  __shared__ float Wl[64][32];
  __shared__ float al[32];
  int t = threadIdx.x;
#pragma unroll
  for (int i = 0; i < 8; ++i) {
    int idx = t + 256 * i;
    Wl[idx >> 5][idx & 31] = W_lin[idx];
  }
  if (t < 32) al[t] = a_vec[t];
  int g = t >> 5, n = t & 31;
  long row = (long)blockIdx.x * 8 + g;
  long o = row * 32 + n;
  __syncthreads();

  out[o] = dinv_uu[row] * (pu[o] + pu[262144 + o]);  // node_embed_u

  float sdu = 0.f;
#pragma unroll
  for (int cc = 0; cc < 8; ++cc) sdu += rs_part[(long)cc * N_NODES + row];
  float du = rsqrtf(sdu);

  float h1 = dinv_cc[row] * (pc[o] + pc[262144 + o]);
  float h2 = du * (pq[o] + pq[262144 + o]);
  float xv = X_C[o];
  float s1 = 0.f, s2 = 0.f, sx = 0.f;
#pragma unroll
  for (int k = 0; k < 32; ++k) {
    float h1k = __shfl(h1, k, 32);
    float h2k = __shfl(h2, k, 32);
    float xk = __shfl(xv, k, 32);
    float w0 = Wl[k][n], w1 = Wl[32 + k][n];
    s1 += h1k * w0;
    s2 += h2k * w0;
    sx += xk * w1;
  }
  float t1 = fmaxf(s1 + sx, 0.f) * al[n];
  float t2 = fmaxf(s2 + sx, 0.f) * al[n];
#pragma unroll
  for (int off = 16; off >= 1; off >>= 1) {
    t1 += __shfl_xor(t1, off, 32);
    t2 += __shfl_xor(t2, off, 32);
  }
  float mx = fmaxf(t1, t2);
  float e1 = expf(t1 - mx), e2 = expf(t2 - mx);
  float inv = 1.0f / (e1 + e2);
  float yc = e1 * inv * h1, yu = e2 * inv * h2;
  out[262144 + o] = yc + yu;  // node_embed_c
  out[524288 + o] = yc;       // Y_c
  out[786432 + o] = yu;       // Y_u
}

extern "C" void kernel_launch(void* const* d_in, const int* in_sizes, int n_in,
                              void* d_out, int out_size, void* d_ws, size_t ws_size,
                              hipStream_t stream) {
  (void)in_sizes; (void)n_in; (void)out_size; (void)ws_size;
  const float* X_U = (const float*)d_in[0];
  const float* X_C = (const float*)d_in[1];
  const float* adj_uu = (const float*)d_in[2];
  const float* adj_uc = (const float*)d_in[3];
  const float* adj_cc = (const float*)d_in[4];
  const float* weight_s = (const float*)d_in[5];
  const float* proj_u = (const float*)d_in[6];
  // d_in[7] = proj_c, unused in forward math
  const float* weight_c = (const float*)d_in[8];
  const float* W_lin = (const float*)d_in[9];
  const float* a_vec = (const float*)d_in[10];
  float* out = (float*)d_out;

  char* ws = (char*)d_ws;
  auto alloc = [&](size_t bytes) {
    char* p = ws;
    ws += (bytes + 255) & ~(size_t)255;
    return p;
  };
  float* dinv_uu = (float*)alloc(8192 * 4);
  float* dinv_cc = (float*)alloc(8192 * 4);
  float* rs_part = (float*)alloc((size_t)8 * 8192 * 4);
  float* cs_part = (float*)alloc((size_t)64 * 8192 * 4);
  float* pu = (float*)alloc((size_t)2 * 262144 * 4);
  float* pc = (float*)alloc((size_t)2 * 262144 * 4);
  float* pq = (float*)alloc((size_t)2 * 262144 * 4);
  short* bt_uu = (short*)alloc((size_t)262144 * 2);
  short* bt_cc = (short*)alloc((size_t)262144 * 2);
  short* bt_uc = (short*)alloc((size_t)262144 * 2);

  hipLaunchKernelGGL(k_degrees, dim3(4608), dim3(256), 0, stream,
                     adj_uu, adj_cc, adj_uc, dinv_uu, dinv_cc, rs_part, cs_part);
  hipLaunchKernelGGL(k_support, dim3(1024, 3), dim3(256), 0, stream,
                     X_U, X_C, weight_s, proj_u, weight_c, dinv_uu, dinv_cc,
                     cs_part, bt_uu, bt_cc, bt_uc);
  hipLaunchKernelGGL(k_gemm, dim3(768), dim3(256), 0, stream,
                     adj_uu, adj_cc, adj_uc, bt_uu, bt_cc, bt_uc, pu, pc, pq);
  hipLaunchKernelGGL(k_epilogue, dim3(1024), dim3(256), 0, stream,
                     pu, pc, pq, dinv_uu, dinv_cc, rs_part, X_C, W_lin, a_vec, out);
}